// Round 1
// baseline (3624.059 us; speedup 1.0000x reference)
//
#include <hip/hip_runtime.h>

#define N_NODES   50000
#define N_EDGES   600000
#define IN_CH     300
#define HID       128
#define N_CLASSES 2
#define N_GRAPHS  128
#define BN_EPS    1e-5f

// ---------------------------------------------------------------------------
// degree kernels
// ---------------------------------------------------------------------------
__global__ __launch_bounds__(256) void deg_kernel(const int* __restrict__ dst,
                                                  float* __restrict__ deg) {
    int e = blockIdx.x * 256 + threadIdx.x;
    if (e < N_EDGES) atomicAdd(&deg[dst[e]], 1.0f);
}

__global__ __launch_bounds__(256) void invdeg_kernel(float* __restrict__ deg) {
    int i = blockIdx.x * 256 + threadIdx.x;
    if (i < N_NODES) deg[i] = 1.0f / fmaxf(deg[i], 1.0f);
}

// ---------------------------------------------------------------------------
// fp32 tiled GEMM: C(M x 128) = A(M x K) @ B(K x 128) [+ bias]
// BM=64, BN=128 (full), BK=16, 256 threads, 8x4 micro-tile per thread.
// ---------------------------------------------------------------------------
#define GBM 64
#define GBK 16

__global__ __launch_bounds__(256) void gemm128(const float* __restrict__ A,
                                               const float* __restrict__ B,
                                               const float* __restrict__ bias,
                                               float* __restrict__ C,
                                               int M, int K) {
    __shared__ float As[GBK][GBM];
    __shared__ float Bs[GBK][HID];

    const int tid = threadIdx.x;
    const int m0  = blockIdx.x * GBM;

    const int tx = tid & 31;   // 32 col-groups of 4
    const int ty = tid >> 5;   // 8 row-groups of 8

    const int arow = tid >> 2;          // 0..63
    const int acol = (tid & 3) * 4;     // 0,4,8,12
    const int brow = tid >> 5;          // 0..7 (also +8)
    const int bcol = (tid & 31) * 4;

    float acc[8][4];
#pragma unroll
    for (int i = 0; i < 8; ++i)
#pragma unroll
        for (int j = 0; j < 4; ++j) acc[i][j] = 0.0f;

    for (int k0 = 0; k0 < K; k0 += GBK) {
        // ---- stage A tile (transposed to As[k][m]) ----
        {
            int gm = m0 + arow;
            int gk = k0 + acol;
            float4 v = make_float4(0.f, 0.f, 0.f, 0.f);
            if (gm < M) {
                if (gk + 3 < K) {
                    v = *(const float4*)&A[(long)gm * K + gk];
                } else {
                    if (gk + 0 < K) v.x = A[(long)gm * K + gk + 0];
                    if (gk + 1 < K) v.y = A[(long)gm * K + gk + 1];
                    if (gk + 2 < K) v.z = A[(long)gm * K + gk + 2];
                    if (gk + 3 < K) v.w = A[(long)gm * K + gk + 3];
                }
            }
            As[acol + 0][arow] = v.x;
            As[acol + 1][arow] = v.y;
            As[acol + 2][arow] = v.z;
            As[acol + 3][arow] = v.w;
        }
        // ---- stage B tile ----
        {
            int gk = k0 + brow;
            float4 v = (gk < K) ? *(const float4*)&B[(long)gk * HID + bcol]
                                : make_float4(0.f, 0.f, 0.f, 0.f);
            *(float4*)&Bs[brow][bcol] = v;
            gk = k0 + brow + 8;
            float4 v2 = (gk < K) ? *(const float4*)&B[(long)gk * HID + bcol]
                                 : make_float4(0.f, 0.f, 0.f, 0.f);
            *(float4*)&Bs[brow + 8][bcol] = v2;
        }
        __syncthreads();

#pragma unroll
        for (int kk = 0; kk < GBK; ++kk) {
            float4 a0 = *(const float4*)&As[kk][ty * 8];
            float4 a1 = *(const float4*)&As[kk][ty * 8 + 4];
            float4 b  = *(const float4*)&Bs[kk][tx * 4];
            float av[8] = {a0.x, a0.y, a0.z, a0.w, a1.x, a1.y, a1.z, a1.w};
            float bv[4] = {b.x, b.y, b.z, b.w};
#pragma unroll
            for (int i = 0; i < 8; ++i)
#pragma unroll
                for (int j = 0; j < 4; ++j) acc[i][j] += av[i] * bv[j];
        }
        __syncthreads();
    }

    float4 b4 = make_float4(0.f, 0.f, 0.f, 0.f);
    if (bias) b4 = *(const float4*)&bias[tx * 4];
#pragma unroll
    for (int i = 0; i < 8; ++i) {
        int gm = m0 + ty * 8 + i;
        if (gm < M) {
            float4 o;
            o.x = acc[i][0] + b4.x;
            o.y = acc[i][1] + b4.y;
            o.z = acc[i][2] + b4.z;
            o.w = acc[i][3] + b4.w;
            *(float4*)&C[(long)gm * HID + tx * 4] = o;
        }
    }
}

// ---------------------------------------------------------------------------
// scatter: out[dst] += Pl[src] * inv_deg[dst]   (32 threads/edge, 4 ch each)
// ---------------------------------------------------------------------------
__global__ __launch_bounds__(256) void scatter_add(const float* __restrict__ Pl,
                                                   const int* __restrict__ src,
                                                   const int* __restrict__ dst,
                                                   const float* __restrict__ invdeg,
                                                   float* __restrict__ out) {
    long t = (long)blockIdx.x * 256 + threadIdx.x;
    int  e = (int)(t >> 5);
    if (e >= N_EDGES) return;
    int q = (int)(t & 31) * 4;
    int s = src[e];
    int d = dst[e];
    float w = invdeg[d];
    float4 v = *(const float4*)&Pl[(long)s * HID + q];
    float* o = &out[(long)d * HID + q];
    atomicAdd(o + 0, v.x * w);
    atomicAdd(o + 1, v.y * w);
    atomicAdd(o + 2, v.z * w);
    atomicAdd(o + 3, v.w * w);
}

// ---------------------------------------------------------------------------
// BatchNorm: stats -> finalize -> apply(+ReLU, in place)
// ---------------------------------------------------------------------------
__global__ __launch_bounds__(256) void bn_stats(const float* __restrict__ h,
                                                float* __restrict__ sums) {
    int c    = threadIdx.x & 127;
    int half = threadIdx.x >> 7;  // 0/1
    float s = 0.f, s2 = 0.f;
    for (int r = blockIdx.x * 2 + half; r < N_NODES; r += gridDim.x * 2) {
        float v = h[(long)r * HID + c];
        s  += v;
        s2 += v * v;
    }
    atomicAdd(&sums[c], s);
    atomicAdd(&sums[HID + c], s2);
}

__global__ __launch_bounds__(128) void bn_finalize(const float* __restrict__ sums,
                                                   const float* __restrict__ gamma,
                                                   const float* __restrict__ beta,
                                                   float* __restrict__ ss) {
    int c = threadIdx.x;
    const float invn = 1.0f / (float)N_NODES;
    float mu  = sums[c] * invn;
    float var = sums[HID + c] * invn - mu * mu;
    float sc  = gamma[c] * rsqrtf(var + BN_EPS);
    ss[c]       = sc;
    ss[HID + c] = beta[c] - mu * sc;
}

__global__ __launch_bounds__(256) void bn_apply_relu(float* __restrict__ h,
                                                     const float* __restrict__ ss) {
    long i = (long)blockIdx.x * 256 + threadIdx.x;
    if (i >= (long)N_NODES * 32) return;  // 32 float4 per row
    int c4 = (int)(i & 31) * 4;
    float4 v  = *(float4*)&h[i * 4];
    float4 sc = *(const float4*)&ss[c4];
    float4 sh = *(const float4*)&ss[HID + c4];
    v.x = fmaxf(v.x * sc.x + sh.x, 0.f);
    v.y = fmaxf(v.y * sc.y + sh.y, 0.f);
    v.z = fmaxf(v.z * sc.z + sh.z, 0.f);
    v.w = fmaxf(v.w * sc.w + sh.w, 0.f);
    *(float4*)&h[i * 4] = v;
}

// ---------------------------------------------------------------------------
// global mean pool (batch sorted -> per-block run-length partial sums)
// ---------------------------------------------------------------------------
#define POOL_ROWS 128
__global__ __launch_bounds__(128) void pool_kernel(const float* __restrict__ h,
                                                   const int* __restrict__ batch,
                                                   float* __restrict__ pooled,
                                                   float* __restrict__ cnt) {
    int c  = threadIdx.x;
    int r0 = blockIdx.x * POOL_ROWS;
    if (r0 >= N_NODES) return;
    int r1 = min(r0 + POOL_ROWS, N_NODES);
    int cur = batch[r0];
    float acc = 0.f, n = 0.f;
    for (int r = r0; r < r1; ++r) {
        int b = batch[r];
        if (b != cur) {
            atomicAdd(&pooled[cur * HID + c], acc);
            if (c == 0) atomicAdd(&cnt[cur], n);
            acc = 0.f;
            n   = 0.f;
            cur = b;
        }
        acc += h[(long)r * HID + c];
        n   += 1.f;
    }
    atomicAdd(&pooled[cur * HID + c], acc);
    if (c == 0) atomicAdd(&cnt[cur], n);
}

// ---------------------------------------------------------------------------
// head: hg = pooled/cnt ; out = hg @ Wc + bc ; writes [out | hg] to d_out
// ---------------------------------------------------------------------------
__global__ __launch_bounds__(128) void head_kernel(const float* __restrict__ pooled,
                                                   const float* __restrict__ cnt,
                                                   const float* __restrict__ Wc,
                                                   const float* __restrict__ bc,
                                                   float* __restrict__ out) {
    int g = threadIdx.x;  // 128 graphs
    float inv = 1.0f / fmaxf(cnt[g], 1.0f);
    float o0 = bc[0], o1 = bc[1];
    for (int c = 0; c < HID; ++c) {
        float v = pooled[g * HID + c] * inv;
        out[N_GRAPHS * N_CLASSES + g * HID + c] = v;  // hg
        o0 += v * Wc[c * 2 + 0];
        o1 += v * Wc[c * 2 + 1];
    }
    out[g * 2 + 0] = o0;
    out[g * 2 + 1] = o1;
}

// ---------------------------------------------------------------------------
// launch
// ---------------------------------------------------------------------------
extern "C" void kernel_launch(void* const* d_in, const int* in_sizes, int n_in,
                              void* d_out, int out_size, void* d_ws, size_t ws_size,
                              hipStream_t stream) {
    const float* x     = (const float*)d_in[0];
    const int*   ei    = (const int*)d_in[1];
    const int*   batch = (const int*)d_in[2];
    const float* W1l = (const float*)d_in[3];
    const float* W1r = (const float*)d_in[4];
    const float* b1  = (const float*)d_in[5];
    const float* g1  = (const float*)d_in[6];
    const float* be1 = (const float*)d_in[7];
    const float* W2l = (const float*)d_in[8];
    const float* W2r = (const float*)d_in[9];
    const float* b2  = (const float*)d_in[10];
    const float* g2  = (const float*)d_in[11];
    const float* be2 = (const float*)d_in[12];
    const float* W3l = (const float*)d_in[13];
    const float* W3r = (const float*)d_in[14];
    const float* b3  = (const float*)d_in[15];
    const float* g3  = (const float*)d_in[16];
    const float* be3 = (const float*)d_in[17];
    const float* Wc  = (const float*)d_in[18];
    const float* bc  = (const float*)d_in[19];

    const int* src = ei;
    const int* dst = ei + N_EDGES;

    float* ws = (float*)d_ws;
    const long FEAT = (long)N_NODES * HID;  // 6.4M floats
    float* buf0   = ws;                 // Pl scratch
    float* buf1   = ws + FEAT;          // pre/h layer 1 & 3
    float* buf2   = ws + 2 * FEAT;      // pre/h layer 2
    float* deg    = ws + 3 * FEAT;      // 50000
    float* sums   = deg + N_NODES;      // 256
    float* ss     = sums + 2 * HID;     // 256
    float* pooled = ss + 2 * HID;       // 16384
    float* cnt    = pooled + N_GRAPHS * HID;  // 128

    float* outp = (float*)d_out;

    const int gemm_grid    = (N_NODES + GBM - 1) / GBM;          // 782
    const int scatter_grid = (N_EDGES * 32 + 255) / 256;         // 75000
    const int apply_grid   = (int)(((long)N_NODES * 32 + 255) / 256);
    const int pool_grid    = (N_NODES + POOL_ROWS - 1) / POOL_ROWS;

    // --- degree (shared across layers) ---
    hipMemsetAsync(deg, 0, N_NODES * sizeof(float), stream);
    deg_kernel<<<(N_EDGES + 255) / 256, 256, 0, stream>>>(dst, deg);
    invdeg_kernel<<<(N_NODES + 255) / 256, 256, 0, stream>>>(deg);

    // ---------------- layer 1 (input x, K=300) ----------------
    gemm128<<<gemm_grid, 256, 0, stream>>>(x, W1l, nullptr, buf0, N_NODES, IN_CH);
    gemm128<<<gemm_grid, 256, 0, stream>>>(x, W1r, b1, buf1, N_NODES, IN_CH);
    scatter_add<<<scatter_grid, 256, 0, stream>>>(buf0, src, dst, deg, buf1);
    hipMemsetAsync(sums, 0, 2 * HID * sizeof(float), stream);
    bn_stats<<<256, 256, 0, stream>>>(buf1, sums);
    bn_finalize<<<1, 128, 0, stream>>>(sums, g1, be1, ss);
    bn_apply_relu<<<apply_grid, 256, 0, stream>>>(buf1, ss);

    // ---------------- layer 2 (input buf1, K=128) ----------------
    gemm128<<<gemm_grid, 256, 0, stream>>>(buf1, W2l, nullptr, buf0, N_NODES, HID);
    gemm128<<<gemm_grid, 256, 0, stream>>>(buf1, W2r, b2, buf2, N_NODES, HID);
    scatter_add<<<scatter_grid, 256, 0, stream>>>(buf0, src, dst, deg, buf2);
    hipMemsetAsync(sums, 0, 2 * HID * sizeof(float), stream);
    bn_stats<<<256, 256, 0, stream>>>(buf2, sums);
    bn_finalize<<<1, 128, 0, stream>>>(sums, g2, be2, ss);
    bn_apply_relu<<<apply_grid, 256, 0, stream>>>(buf2, ss);

    // ---------------- layer 3 (input buf2, K=128) ----------------
    gemm128<<<gemm_grid, 256, 0, stream>>>(buf2, W3l, nullptr, buf0, N_NODES, HID);
    gemm128<<<gemm_grid, 256, 0, stream>>>(buf2, W3r, b3, buf1, N_NODES, HID);
    scatter_add<<<scatter_grid, 256, 0, stream>>>(buf0, src, dst, deg, buf1);
    hipMemsetAsync(sums, 0, 2 * HID * sizeof(float), stream);
    bn_stats<<<256, 256, 0, stream>>>(buf1, sums);
    bn_finalize<<<1, 128, 0, stream>>>(sums, g3, be3, ss);
    bn_apply_relu<<<apply_grid, 256, 0, stream>>>(buf1, ss);

    // ---------------- pool + head ----------------
    hipMemsetAsync(pooled, 0, (N_GRAPHS * HID + N_GRAPHS) * sizeof(float), stream);
    pool_kernel<<<pool_grid, 128, 0, stream>>>(buf1, batch, pooled, cnt);
    head_kernel<<<1, 128, 0, stream>>>(pooled, cnt, Wc, bc, outp);
}

// Round 2
// 1070.779 us; speedup vs baseline: 3.3845x; 3.3845x over previous
//
#include <hip/hip_runtime.h>

#define N_NODES   50000
#define N_EDGES   600000
#define IN_CH     300
#define HID       128
#define N_CLASSES 2
#define N_GRAPHS  128
#define BN_EPS    1e-5f

// ---------------------------------------------------------------------------
// CSR construction: degree count -> scan -> bucket fill
// ---------------------------------------------------------------------------
__global__ __launch_bounds__(256) void deg_kernel(const int* __restrict__ dst,
                                                  int* __restrict__ ideg) {
    int e = blockIdx.x * 256 + threadIdx.x;
    if (e < N_EDGES) atomicAdd(&ideg[dst[e]], 1);
}

__global__ __launch_bounds__(256) void invdeg_kernel(const int* __restrict__ ideg,
                                                     float* __restrict__ invdeg) {
    int i = blockIdx.x * 256 + threadIdx.x;
    if (i < N_NODES) invdeg[i] = 1.0f / fmaxf((float)ideg[i], 1.0f);
}

#define SCAN_T 1024
__global__ __launch_bounds__(SCAN_T) void scan_kernel(const int* __restrict__ ideg,
                                                      int* __restrict__ row_start) {
    __shared__ int part[SCAN_T];
    int t = threadIdx.x;
    const int chunk = (N_NODES + SCAN_T - 1) / SCAN_T;  // 49
    int b = t * chunk;
    int e = min(b + chunk, N_NODES);
    int s = 0;
    for (int i = b; i < e; ++i) s += ideg[i];
    part[t] = s;
    __syncthreads();
    for (int off = 1; off < SCAN_T; off <<= 1) {
        int v = (t >= off) ? part[t - off] : 0;
        __syncthreads();
        part[t] += v;
        __syncthreads();
    }
    int run = (t == 0) ? 0 : part[t - 1];
    for (int i = b; i < e; ++i) {
        row_start[i] = run;
        run += ideg[i];
    }
    if (t == SCAN_T - 1) row_start[N_NODES] = run;
}

__global__ __launch_bounds__(256) void fill_kernel(const int* __restrict__ src,
                                                   const int* __restrict__ dst,
                                                   const int* __restrict__ row_start,
                                                   int* __restrict__ cursor,
                                                   int* __restrict__ csr_src) {
    int e = blockIdx.x * 256 + threadIdx.x;
    if (e >= N_EDGES) return;
    int d = dst[e];
    int pos = row_start[d] + atomicAdd(&cursor[d], 1);
    csr_src[pos] = src[e];
}

// ---------------------------------------------------------------------------
// fp32 tiled GEMM: C(M x 128) = A(M x K) @ B(K x 128) [+ bias]
// ---------------------------------------------------------------------------
#define GBM 64
#define GBK 16

__global__ __launch_bounds__(256) void gemm128(const float* __restrict__ A,
                                               const float* __restrict__ B,
                                               const float* __restrict__ bias,
                                               float* __restrict__ C,
                                               int M, int K) {
    __shared__ float As[GBK][GBM];
    __shared__ float Bs[GBK][HID];

    const int tid = threadIdx.x;
    const int m0  = blockIdx.x * GBM;

    const int tx = tid & 31;
    const int ty = tid >> 5;

    const int arow = tid >> 2;
    const int acol = (tid & 3) * 4;
    const int brow = tid >> 5;
    const int bcol = (tid & 31) * 4;

    float acc[8][4];
#pragma unroll
    for (int i = 0; i < 8; ++i)
#pragma unroll
        for (int j = 0; j < 4; ++j) acc[i][j] = 0.0f;

    for (int k0 = 0; k0 < K; k0 += GBK) {
        {
            int gm = m0 + arow;
            int gk = k0 + acol;
            float4 v = make_float4(0.f, 0.f, 0.f, 0.f);
            if (gm < M) {
                if (gk + 3 < K) {
                    v = *(const float4*)&A[(long)gm * K + gk];
                } else {
                    if (gk + 0 < K) v.x = A[(long)gm * K + gk + 0];
                    if (gk + 1 < K) v.y = A[(long)gm * K + gk + 1];
                    if (gk + 2 < K) v.z = A[(long)gm * K + gk + 2];
                    if (gk + 3 < K) v.w = A[(long)gm * K + gk + 3];
                }
            }
            As[acol + 0][arow] = v.x;
            As[acol + 1][arow] = v.y;
            As[acol + 2][arow] = v.z;
            As[acol + 3][arow] = v.w;
        }
        {
            int gk = k0 + brow;
            float4 v = (gk < K) ? *(const float4*)&B[(long)gk * HID + bcol]
                                : make_float4(0.f, 0.f, 0.f, 0.f);
            *(float4*)&Bs[brow][bcol] = v;
            gk = k0 + brow + 8;
            float4 v2 = (gk < K) ? *(const float4*)&B[(long)gk * HID + bcol]
                                 : make_float4(0.f, 0.f, 0.f, 0.f);
            *(float4*)&Bs[brow + 8][bcol] = v2;
        }
        __syncthreads();

#pragma unroll
        for (int kk = 0; kk < GBK; ++kk) {
            float4 a0 = *(const float4*)&As[kk][ty * 8];
            float4 a1 = *(const float4*)&As[kk][ty * 8 + 4];
            float4 b  = *(const float4*)&Bs[kk][tx * 4];
            float av[8] = {a0.x, a0.y, a0.z, a0.w, a1.x, a1.y, a1.z, a1.w};
            float bv[4] = {b.x, b.y, b.z, b.w};
#pragma unroll
            for (int i = 0; i < 8; ++i)
#pragma unroll
                for (int j = 0; j < 4; ++j) acc[i][j] += av[i] * bv[j];
        }
        __syncthreads();
    }

    float4 b4 = make_float4(0.f, 0.f, 0.f, 0.f);
    if (bias) b4 = *(const float4*)&bias[tx * 4];
#pragma unroll
    for (int i = 0; i < 8; ++i) {
        int gm = m0 + ty * 8 + i;
        if (gm < M) {
            float4 o;
            o.x = acc[i][0] + b4.x;
            o.y = acc[i][1] + b4.y;
            o.z = acc[i][2] + b4.z;
            o.w = acc[i][3] + b4.w;
            *(float4*)&C[(long)gm * HID + tx * 4] = o;
        }
    }
}

// ---------------------------------------------------------------------------
// CSR gather aggregation: out[n] += invdeg[n] * sum_{j in adj(n)} Pl[csr_src[j]]
// 128 threads per node (one per channel), 2 nodes per block.
// ---------------------------------------------------------------------------
__global__ __launch_bounds__(256) void gather_agg(const float* __restrict__ Pl,
                                                  const int* __restrict__ row_start,
                                                  const int* __restrict__ csr_src,
                                                  const float* __restrict__ invdeg,
                                                  float* __restrict__ out) {
    int c = threadIdx.x;             // channel 0..127
    int node = blockIdx.x * 2 + threadIdx.y;
    if (node >= N_NODES) return;
    int beg = row_start[node];
    int end = row_start[node + 1];
    float s = 0.f;
    for (int j = beg; j < end; ++j) {
        int sn = csr_src[j];
        s += Pl[(long)sn * HID + c];
    }
    out[(long)node * HID + c] += s * invdeg[node];
}

// ---------------------------------------------------------------------------
// BatchNorm: stats -> finalize -> apply(+ReLU, in place)
// ---------------------------------------------------------------------------
__global__ __launch_bounds__(256) void bn_stats(const float* __restrict__ h,
                                                float* __restrict__ sums) {
    int c    = threadIdx.x & 127;
    int half = threadIdx.x >> 7;
    float s = 0.f, s2 = 0.f;
    for (int r = blockIdx.x * 2 + half; r < N_NODES; r += gridDim.x * 2) {
        float v = h[(long)r * HID + c];
        s  += v;
        s2 += v * v;
    }
    atomicAdd(&sums[c], s);
    atomicAdd(&sums[HID + c], s2);
}

__global__ __launch_bounds__(128) void bn_finalize(const float* __restrict__ sums,
                                                   const float* __restrict__ gamma,
                                                   const float* __restrict__ beta,
                                                   float* __restrict__ ss) {
    int c = threadIdx.x;
    const float invn = 1.0f / (float)N_NODES;
    float mu  = sums[c] * invn;
    float var = sums[HID + c] * invn - mu * mu;
    float sc  = gamma[c] * rsqrtf(var + BN_EPS);
    ss[c]       = sc;
    ss[HID + c] = beta[c] - mu * sc;
}

__global__ __launch_bounds__(256) void bn_apply_relu(float* __restrict__ h,
                                                     const float* __restrict__ ss) {
    long i = (long)blockIdx.x * 256 + threadIdx.x;
    if (i >= (long)N_NODES * 32) return;
    int c4 = (int)(i & 31) * 4;
    float4 v  = *(float4*)&h[i * 4];
    float4 sc = *(const float4*)&ss[c4];
    float4 sh = *(const float4*)&ss[HID + c4];
    v.x = fmaxf(v.x * sc.x + sh.x, 0.f);
    v.y = fmaxf(v.y * sc.y + sh.y, 0.f);
    v.z = fmaxf(v.z * sc.z + sh.z, 0.f);
    v.w = fmaxf(v.w * sc.w + sh.w, 0.f);
    *(float4*)&h[i * 4] = v;
}

// ---------------------------------------------------------------------------
// global mean pool
// ---------------------------------------------------------------------------
#define POOL_ROWS 128
__global__ __launch_bounds__(128) void pool_kernel(const float* __restrict__ h,
                                                   const int* __restrict__ batch,
                                                   float* __restrict__ pooled,
                                                   float* __restrict__ cnt) {
    int c  = threadIdx.x;
    int r0 = blockIdx.x * POOL_ROWS;
    if (r0 >= N_NODES) return;
    int r1 = min(r0 + POOL_ROWS, N_NODES);
    int cur = batch[r0];
    float acc = 0.f, n = 0.f;
    for (int r = r0; r < r1; ++r) {
        int b = batch[r];
        if (b != cur) {
            atomicAdd(&pooled[cur * HID + c], acc);
            if (c == 0) atomicAdd(&cnt[cur], n);
            acc = 0.f;
            n   = 0.f;
            cur = b;
        }
        acc += h[(long)r * HID + c];
        n   += 1.f;
    }
    atomicAdd(&pooled[cur * HID + c], acc);
    if (c == 0) atomicAdd(&cnt[cur], n);
}

// ---------------------------------------------------------------------------
// head
// ---------------------------------------------------------------------------
__global__ __launch_bounds__(128) void head_kernel(const float* __restrict__ pooled,
                                                   const float* __restrict__ cnt,
                                                   const float* __restrict__ Wc,
                                                   const float* __restrict__ bc,
                                                   float* __restrict__ out) {
    int g = threadIdx.x;
    float inv = 1.0f / fmaxf(cnt[g], 1.0f);
    float o0 = bc[0], o1 = bc[1];
    for (int c = 0; c < HID; ++c) {
        float v = pooled[g * HID + c] * inv;
        out[N_GRAPHS * N_CLASSES + g * HID + c] = v;
        o0 += v * Wc[c * 2 + 0];
        o1 += v * Wc[c * 2 + 1];
    }
    out[g * 2 + 0] = o0;
    out[g * 2 + 1] = o1;
}

// ---------------------------------------------------------------------------
// launch
// ---------------------------------------------------------------------------
extern "C" void kernel_launch(void* const* d_in, const int* in_sizes, int n_in,
                              void* d_out, int out_size, void* d_ws, size_t ws_size,
                              hipStream_t stream) {
    const float* x     = (const float*)d_in[0];
    const int*   ei    = (const int*)d_in[1];
    const int*   batch = (const int*)d_in[2];
    const float* W1l = (const float*)d_in[3];
    const float* W1r = (const float*)d_in[4];
    const float* b1  = (const float*)d_in[5];
    const float* g1  = (const float*)d_in[6];
    const float* be1 = (const float*)d_in[7];
    const float* W2l = (const float*)d_in[8];
    const float* W2r = (const float*)d_in[9];
    const float* b2  = (const float*)d_in[10];
    const float* g2  = (const float*)d_in[11];
    const float* be2 = (const float*)d_in[12];
    const float* W3l = (const float*)d_in[13];
    const float* W3r = (const float*)d_in[14];
    const float* b3  = (const float*)d_in[15];
    const float* g3  = (const float*)d_in[16];
    const float* be3 = (const float*)d_in[17];
    const float* Wc  = (const float*)d_in[18];
    const float* bc  = (const float*)d_in[19];

    const int* src = ei;
    const int* dst = ei + N_EDGES;

    float* ws = (float*)d_ws;
    const long FEAT = (long)N_NODES * HID;  // 6.4M floats
    float* buf0 = ws;
    float* buf1 = ws + FEAT;
    float* buf2 = ws + 2 * FEAT;
    int*   ideg      = (int*)(ws + 3 * FEAT);        // 50000
    int*   row_start = ideg + N_NODES;               // 50001
    int*   cursor    = row_start + N_NODES + 1;      // 50000
    int*   csr_src   = cursor + N_NODES;             // 600000
    float* invdeg    = (float*)(csr_src + N_EDGES);  // 50000
    float* sums      = invdeg + N_NODES;             // 256
    float* ss        = sums + 2 * HID;               // 256
    float* pooled    = ss + 2 * HID;                 // 16384
    float* cnt       = pooled + N_GRAPHS * HID;      // 128

    float* outp = (float*)d_out;

    const int gemm_grid   = (N_NODES + GBM - 1) / GBM;
    const int gather_grid = (N_NODES + 1) / 2;
    const int apply_grid  = (int)(((long)N_NODES * 32 + 255) / 256);
    const int pool_grid   = (N_NODES + POOL_ROWS - 1) / POOL_ROWS;
    const dim3 gather_blk(128, 2);

    // --- CSR build (once per call) ---
    hipMemsetAsync(ideg, 0, 2 * N_NODES * sizeof(int) + sizeof(int), stream);  // ideg + row_start[0..] partial
    hipMemsetAsync(cursor, 0, N_NODES * sizeof(int), stream);
    deg_kernel<<<(N_EDGES + 255) / 256, 256, 0, stream>>>(dst, ideg);
    invdeg_kernel<<<(N_NODES + 255) / 256, 256, 0, stream>>>(ideg, invdeg);
    scan_kernel<<<1, SCAN_T, 0, stream>>>(ideg, row_start);
    fill_kernel<<<(N_EDGES + 255) / 256, 256, 0, stream>>>(src, dst, row_start, cursor, csr_src);

    // ---------------- layer 1 (input x, K=300) ----------------
    gemm128<<<gemm_grid, 256, 0, stream>>>(x, W1l, nullptr, buf0, N_NODES, IN_CH);
    gemm128<<<gemm_grid, 256, 0, stream>>>(x, W1r, b1, buf1, N_NODES, IN_CH);
    gather_agg<<<gather_grid, gather_blk, 0, stream>>>(buf0, row_start, csr_src, invdeg, buf1);
    hipMemsetAsync(sums, 0, 2 * HID * sizeof(float), stream);
    bn_stats<<<256, 256, 0, stream>>>(buf1, sums);
    bn_finalize<<<1, 128, 0, stream>>>(sums, g1, be1, ss);
    bn_apply_relu<<<apply_grid, 256, 0, stream>>>(buf1, ss);

    // ---------------- layer 2 (input buf1, K=128) ----------------
    gemm128<<<gemm_grid, 256, 0, stream>>>(buf1, W2l, nullptr, buf0, N_NODES, HID);
    gemm128<<<gemm_grid, 256, 0, stream>>>(buf1, W2r, b2, buf2, N_NODES, HID);
    gather_agg<<<gather_grid, gather_blk, 0, stream>>>(buf0, row_start, csr_src, invdeg, buf2);
    hipMemsetAsync(sums, 0, 2 * HID * sizeof(float), stream);
    bn_stats<<<256, 256, 0, stream>>>(buf2, sums);
    bn_finalize<<<1, 128, 0, stream>>>(sums, g2, be2, ss);
    bn_apply_relu<<<apply_grid, 256, 0, stream>>>(buf2, ss);

    // ---------------- layer 3 (input buf2, K=128) ----------------
    gemm128<<<gemm_grid, 256, 0, stream>>>(buf2, W3l, nullptr, buf0, N_NODES, HID);
    gemm128<<<gemm_grid, 256, 0, stream>>>(buf2, W3r, b3, buf1, N_NODES, HID);
    gather_agg<<<gather_grid, gather_blk, 0, stream>>>(buf0, row_start, csr_src, invdeg, buf1);
    hipMemsetAsync(sums, 0, 2 * HID * sizeof(float), stream);
    bn_stats<<<256, 256, 0, stream>>>(buf1, sums);
    bn_finalize<<<1, 128, 0, stream>>>(sums, g3, be3, ss);
    bn_apply_relu<<<apply_grid, 256, 0, stream>>>(buf1, ss);

    // ---------------- pool + head ----------------
    hipMemsetAsync(pooled, 0, (N_GRAPHS * HID + N_GRAPHS) * sizeof(float), stream);
    pool_kernel<<<pool_grid, 128, 0, stream>>>(buf1, batch, pooled, cnt);
    head_kernel<<<1, 128, 0, stream>>>(pooled, cnt, Wc, bc, outp);
}

// Round 3
// 780.001 us; speedup vs baseline: 4.6462x; 1.3728x over previous
//
#include <hip/hip_runtime.h>

#define N_NODES   50000
#define N_EDGES   600000
#define IN_CH     300
#define HID       128
#define N_CLASSES 2
#define N_GRAPHS  128
#define BN_EPS    1e-5f

typedef __attribute__((ext_vector_type(8))) short bf8_t;   // 8 bf16 (4 VGPRs)
typedef __attribute__((ext_vector_type(4))) float f4_t;    // MFMA acc

// bf16 round-to-nearest-even helpers
__device__ __forceinline__ unsigned short f2bf(float x) {
    union { float f; unsigned u; } q; q.f = x;
    unsigned r = q.u + 0x7fffu + ((q.u >> 16) & 1u);
    return (unsigned short)(r >> 16);
}
__device__ __forceinline__ float bf2f(unsigned short h) {
    union { float f; unsigned u; } q; q.u = ((unsigned)h) << 16; return q.f;
}

// ---------------------------------------------------------------------------
// CSR construction: degree count -> scan -> bucket fill
// ---------------------------------------------------------------------------
__global__ __launch_bounds__(256) void deg_kernel(const int* __restrict__ dst,
                                                  int* __restrict__ ideg) {
    int e = blockIdx.x * 256 + threadIdx.x;
    if (e < N_EDGES) atomicAdd(&ideg[dst[e]], 1);
}

__global__ __launch_bounds__(256) void invdeg_kernel(const int* __restrict__ ideg,
                                                     float* __restrict__ invdeg) {
    int i = blockIdx.x * 256 + threadIdx.x;
    if (i < N_NODES) invdeg[i] = 1.0f / fmaxf((float)ideg[i], 1.0f);
}

#define SCAN_T 1024
__global__ __launch_bounds__(SCAN_T) void scan_kernel(const int* __restrict__ ideg,
                                                      int* __restrict__ row_start) {
    __shared__ int part[SCAN_T];
    int t = threadIdx.x;
    const int chunk = (N_NODES + SCAN_T - 1) / SCAN_T;
    int b = t * chunk;
    int e = min(b + chunk, N_NODES);
    int s = 0;
    for (int i = b; i < e; ++i) s += ideg[i];
    part[t] = s;
    __syncthreads();
    for (int off = 1; off < SCAN_T; off <<= 1) {
        int v = (t >= off) ? part[t - off] : 0;
        __syncthreads();
        part[t] += v;
        __syncthreads();
    }
    int run = (t == 0) ? 0 : part[t - 1];
    for (int i = b; i < e; ++i) {
        row_start[i] = run;
        run += ideg[i];
    }
    if (t == SCAN_T - 1) row_start[N_NODES] = run;
}

__global__ __launch_bounds__(256) void fill_kernel(const int* __restrict__ src,
                                                   const int* __restrict__ dst,
                                                   const int* __restrict__ row_start,
                                                   int* __restrict__ cursor,
                                                   int* __restrict__ csr_src) {
    int e = blockIdx.x * 256 + threadIdx.x;
    if (e >= N_EDGES) return;
    int d = dst[e];
    int pos = row_start[d] + atomicAdd(&cursor[d], 1);
    csr_src[pos] = src[e];
}

// ---------------------------------------------------------------------------
// weight prep: BT[n][k] (256 x Kp, bf16 hi/lo, zero-padded k>=K)
//   n<128 -> Wl[k][n] ; n>=128 -> Wr[k][n-128]
// ---------------------------------------------------------------------------
__global__ __launch_bounds__(256) void prep_w(const float* __restrict__ Wl,
                                              const float* __restrict__ Wr,
                                              int K, int Kp,
                                              unsigned short* __restrict__ Bhi,
                                              unsigned short* __restrict__ Blo) {
    int idx = blockIdx.x * 256 + threadIdx.x;
    if (idx >= 256 * Kp) return;
    int n = idx / Kp;
    int k = idx - n * Kp;
    float v = 0.f;
    if (k < K) v = (n < 128) ? Wl[k * 128 + n] : Wr[k * 128 + (n - 128)];
    unsigned short h = f2bf(v);
    unsigned short l = f2bf(v - bf2f(h));
    Bhi[idx] = h;
    Blo[idx] = l;
}

// ---------------------------------------------------------------------------
// split-bf16 MFMA GEMM:  C0 = A@Wl ,  C1 = A@Wr + bias   (N = 128+128)
// A: M x K fp32 (row-major). B staged as BT hi/lo 256 x Kp bf16.
// block = 4 waves; block tile 64(M) x 256(N); wave tile 64x64 = 4x4 MFMA 16x16x32.
// fp32 emulated via Dekker split: ah*bh + al*bh + ah*bl  (err ~2^-16).
// ---------------------------------------------------------------------------
__global__ __launch_bounds__(256) void gemm_mfma(const float* __restrict__ A,
                                                 int M, int K, int Kp,
                                                 const unsigned short* __restrict__ Bhi,
                                                 const unsigned short* __restrict__ Blo,
                                                 const float* __restrict__ bias,
                                                 float* __restrict__ C0,
                                                 float* __restrict__ C1) {
    const int lane = threadIdx.x & 63;
    const int wave = threadIdx.x >> 6;
    const int l16  = lane & 15;
    const int quad = lane >> 4;
    const long m0  = (long)blockIdx.x * 64;
    const int  n0  = wave * 64;

    f4_t acc[4][4];
#pragma unroll
    for (int mt = 0; mt < 4; ++mt)
#pragma unroll
        for (int nt = 0; nt < 4; ++nt) acc[mt][nt] = (f4_t){0.f, 0.f, 0.f, 0.f};

    long arow[4];
#pragma unroll
    for (int mt = 0; mt < 4; ++mt) {
        long r = m0 + mt * 16 + l16;
        arow[mt] = (r < M) ? r : (long)(M - 1);  // clamp; clamped rows never stored
    }

    for (int k0 = 0; k0 < K; k0 += 32) {
        bf8_t ah[4], al[4];
        const bool full = (k0 + 32 <= K);  // wave-uniform
#pragma unroll
        for (int mt = 0; mt < 4; ++mt) {
            float f[8];
            const float* p = A + arow[mt] * K + k0 + quad * 8;
            if (full) {
                float4 u0 = *(const float4*)p;        // K=300 -> row stride 1200B (16B mult); K=128 -> 512B
                float4 u1 = *(const float4*)(p + 4);
                f[0] = u0.x; f[1] = u0.y; f[2] = u0.z; f[3] = u0.w;
                f[4] = u1.x; f[5] = u1.y; f[6] = u1.z; f[7] = u1.w;
            } else {
#pragma unroll
                for (int j = 0; j < 8; ++j) {
                    int kk = k0 + quad * 8 + j;
                    f[j] = (kk < K) ? A[arow[mt] * K + kk] : 0.f;
                }
            }
#pragma unroll
            for (int j = 0; j < 8; ++j) {
                unsigned short h = f2bf(f[j]);
                unsigned short l = f2bf(f[j] - bf2f(h));
                ah[mt][j] = (short)h;
                al[mt][j] = (short)l;
            }
        }
#pragma unroll
        for (int nt = 0; nt < 4; ++nt) {
            long nrow = (long)(n0 + nt * 16 + l16);
            const unsigned short* pb = Bhi + nrow * Kp + k0 + quad * 8;
            const unsigned short* ql = Blo + nrow * Kp + k0 + quad * 8;
            bf8_t bh = *(const bf8_t*)pb;
            bf8_t bl = *(const bf8_t*)ql;
#pragma unroll
            for (int mt = 0; mt < 4; ++mt) {
                acc[mt][nt] = __builtin_amdgcn_mfma_f32_16x16x32_bf16(ah[mt], bh, acc[mt][nt], 0, 0, 0);
                acc[mt][nt] = __builtin_amdgcn_mfma_f32_16x16x32_bf16(al[mt], bh, acc[mt][nt], 0, 0, 0);
                acc[mt][nt] = __builtin_amdgcn_mfma_f32_16x16x32_bf16(ah[mt], bl, acc[mt][nt], 0, 0, 0);
            }
        }
    }

    // epilogue: wave-uniform half selection (n0<128 -> C0, else C1 + bias)
    const bool left = (n0 < 128);
    float* __restrict__ Cb = left ? C0 : C1;
    float badd[4];
    int   ncol[4];
#pragma unroll
    for (int nt = 0; nt < 4; ++nt) {
        int ng = n0 + nt * 16 + l16;
        ncol[nt] = left ? ng : (ng - 128);
        badd[nt] = left ? 0.f : bias[ng - 128];
    }
#pragma unroll
    for (int mt = 0; mt < 4; ++mt) {
#pragma unroll
        for (int r = 0; r < 4; ++r) {
            long row = m0 + mt * 16 + quad * 4 + r;
            if (row < M) {
#pragma unroll
                for (int nt = 0; nt < 4; ++nt)
                    Cb[row * 128 + ncol[nt]] = acc[mt][nt][r] + badd[nt];
            }
        }
    }
}

// ---------------------------------------------------------------------------
// CSR gather: out[n] += invdeg[n] * sum_{j in adj(n)} Pl[csr_src[j]]
// 32 lanes/node (float4/lane), 8 nodes/block, 4-edge unroll for MLP.
// ---------------------------------------------------------------------------
__global__ __launch_bounds__(256) void gather_agg(const float* __restrict__ Pl,
                                                  const int* __restrict__ row_start,
                                                  const int* __restrict__ csr_src,
                                                  const float* __restrict__ invdeg,
                                                  float* __restrict__ out) {
    int slot = threadIdx.x >> 5;
    int lane = threadIdx.x & 31;
    int node = blockIdx.x * 8 + slot;
    if (node >= N_NODES) return;
    int beg = row_start[node];
    int end = row_start[node + 1];
    const float* base = Pl + lane * 4;
    float sx = 0.f, sy = 0.f, sz = 0.f, sw = 0.f;
    int j = beg;
    for (; j + 4 <= end; j += 4) {
        int i0 = csr_src[j + 0];
        int i1 = csr_src[j + 1];
        int i2 = csr_src[j + 2];
        int i3 = csr_src[j + 3];
        float4 v0 = *(const float4*)(base + (long)i0 * HID);
        float4 v1 = *(const float4*)(base + (long)i1 * HID);
        float4 v2 = *(const float4*)(base + (long)i2 * HID);
        float4 v3 = *(const float4*)(base + (long)i3 * HID);
        sx += v0.x + v1.x + v2.x + v3.x;
        sy += v0.y + v1.y + v2.y + v3.y;
        sz += v0.z + v1.z + v2.z + v3.z;
        sw += v0.w + v1.w + v2.w + v3.w;
    }
    for (; j < end; ++j) {
        int i0 = csr_src[j];
        float4 v0 = *(const float4*)(base + (long)i0 * HID);
        sx += v0.x; sy += v0.y; sz += v0.z; sw += v0.w;
    }
    float w = invdeg[node];
    float* o = out + (long)node * HID + lane * 4;
    float4 cur = *(float4*)o;
    cur.x += sx * w;
    cur.y += sy * w;
    cur.z += sz * w;
    cur.w += sw * w;
    *(float4*)o = cur;
}

// ---------------------------------------------------------------------------
// BatchNorm: stats -> finalize -> apply(+ReLU, in place)
// ---------------------------------------------------------------------------
__global__ __launch_bounds__(256) void bn_stats(const float* __restrict__ h,
                                                float* __restrict__ sums) {
    int c    = threadIdx.x & 127;
    int half = threadIdx.x >> 7;
    float s = 0.f, s2 = 0.f;
    for (int r = blockIdx.x * 2 + half; r < N_NODES; r += gridDim.x * 2) {
        float v = h[(long)r * HID + c];
        s  += v;
        s2 += v * v;
    }
    atomicAdd(&sums[c], s);
    atomicAdd(&sums[HID + c], s2);
}

__global__ __launch_bounds__(128) void bn_finalize(const float* __restrict__ sums,
                                                   const float* __restrict__ gamma,
                                                   const float* __restrict__ beta,
                                                   float* __restrict__ ss) {
    int c = threadIdx.x;
    const float invn = 1.0f / (float)N_NODES;
    float mu  = sums[c] * invn;
    float var = sums[HID + c] * invn - mu * mu;
    float sc  = gamma[c] * rsqrtf(var + BN_EPS);
    ss[c]       = sc;
    ss[HID + c] = beta[c] - mu * sc;
}

__global__ __launch_bounds__(256) void bn_apply_relu(float* __restrict__ h,
                                                     const float* __restrict__ ss) {
    long i = (long)blockIdx.x * 256 + threadIdx.x;
    if (i >= (long)N_NODES * 32) return;
    int c4 = (int)(i & 31) * 4;
    float4 v  = *(float4*)&h[i * 4];
    float4 sc = *(const float4*)&ss[c4];
    float4 sh = *(const float4*)&ss[HID + c4];
    v.x = fmaxf(v.x * sc.x + sh.x, 0.f);
    v.y = fmaxf(v.y * sc.y + sh.y, 0.f);
    v.z = fmaxf(v.z * sc.z + sh.z, 0.f);
    v.w = fmaxf(v.w * sc.w + sh.w, 0.f);
    *(float4*)&h[i * 4] = v;
}

// ---------------------------------------------------------------------------
// global mean pool
// ---------------------------------------------------------------------------
#define POOL_ROWS 128
__global__ __launch_bounds__(128) void pool_kernel(const float* __restrict__ h,
                                                   const int* __restrict__ batch,
                                                   float* __restrict__ pooled,
                                                   float* __restrict__ cnt) {
    int c  = threadIdx.x;
    int r0 = blockIdx.x * POOL_ROWS;
    if (r0 >= N_NODES) return;
    int r1 = min(r0 + POOL_ROWS, N_NODES);
    int cur = batch[r0];
    float acc = 0.f, n = 0.f;
    for (int r = r0; r < r1; ++r) {
        int b = batch[r];
        if (b != cur) {
            atomicAdd(&pooled[cur * HID + c], acc);
            if (c == 0) atomicAdd(&cnt[cur], n);
            acc = 0.f;
            n   = 0.f;
            cur = b;
        }
        acc += h[(long)r * HID + c];
        n   += 1.f;
    }
    atomicAdd(&pooled[cur * HID + c], acc);
    if (c == 0) atomicAdd(&cnt[cur], n);
}

// ---------------------------------------------------------------------------
// head
// ---------------------------------------------------------------------------
__global__ __launch_bounds__(128) void head_kernel(const float* __restrict__ pooled,
                                                   const float* __restrict__ cnt,
                                                   const float* __restrict__ Wc,
                                                   const float* __restrict__ bc,
                                                   float* __restrict__ out) {
    int g = threadIdx.x;
    float inv = 1.0f / fmaxf(cnt[g], 1.0f);
    float o0 = bc[0], o1 = bc[1];
    for (int c = 0; c < HID; ++c) {
        float v = pooled[g * HID + c] * inv;
        out[N_GRAPHS * N_CLASSES + g * HID + c] = v;
        o0 += v * Wc[c * 2 + 0];
        o1 += v * Wc[c * 2 + 1];
    }
    out[g * 2 + 0] = o0;
    out[g * 2 + 1] = o1;
}

// ---------------------------------------------------------------------------
// launch
// ---------------------------------------------------------------------------
extern "C" void kernel_launch(void* const* d_in, const int* in_sizes, int n_in,
                              void* d_out, int out_size, void* d_ws, size_t ws_size,
                              hipStream_t stream) {
    const float* x     = (const float*)d_in[0];
    const int*   ei    = (const int*)d_in[1];
    const int*   batch = (const int*)d_in[2];
    const float* W1l = (const float*)d_in[3];
    const float* W1r = (const float*)d_in[4];
    const float* b1  = (const float*)d_in[5];
    const float* g1  = (const float*)d_in[6];
    const float* be1 = (const float*)d_in[7];
    const float* W2l = (const float*)d_in[8];
    const float* W2r = (const float*)d_in[9];
    const float* b2  = (const float*)d_in[10];
    const float* g2  = (const float*)d_in[11];
    const float* be2 = (const float*)d_in[12];
    const float* W3l = (const float*)d_in[13];
    const float* W3r = (const float*)d_in[14];
    const float* b3  = (const float*)d_in[15];
    const float* g3  = (const float*)d_in[16];
    const float* be3 = (const float*)d_in[17];
    const float* Wc  = (const float*)d_in[18];
    const float* bc  = (const float*)d_in[19];

    const int* src = ei;
    const int* dst = ei + N_EDGES;

    float* ws = (float*)d_ws;
    const long FEAT = (long)N_NODES * HID;
    float* buf0 = ws;
    float* buf1 = ws + FEAT;
    float* buf2 = ws + 2 * FEAT;
    int*   ideg      = (int*)(ws + 3 * FEAT);        // 50000
    int*   row_start = ideg + N_NODES;               // 50001
    int*   cursor    = row_start + N_NODES + 1;      // 50000
    int*   csr_src   = cursor + N_NODES;             // 600000
    float* invdeg    = (float*)(csr_src + N_EDGES);  // 50000
    float* sums      = invdeg + N_NODES;             // 256
    float* ss        = sums + 2 * HID;               // 256
    float* pooled    = ss + 2 * HID;                 // 16384
    float* cnt       = pooled + N_GRAPHS * HID;      // 128
    unsigned short* Bhi = (unsigned short*)(cnt + N_GRAPHS);  // 256*320
    unsigned short* Blo = Bhi + 256 * 320;                    // 256*320

    float* outp = (float*)d_out;

    const int KP1 = 320;  // 300 padded to mult of 32
    const int gemm_grid   = (N_NODES + 63) / 64;     // 782
    const int gather_grid = (N_NODES + 7) / 8;
    const int apply_grid  = (int)(((long)N_NODES * 32 + 255) / 256);
    const int pool_grid   = (N_NODES + POOL_ROWS - 1) / POOL_ROWS;

    // --- CSR build (once per call) ---
    hipMemsetAsync(ideg, 0, N_NODES * sizeof(int), stream);
    hipMemsetAsync(cursor, 0, N_NODES * sizeof(int), stream);
    deg_kernel<<<(N_EDGES + 255) / 256, 256, 0, stream>>>(dst, ideg);
    invdeg_kernel<<<(N_NODES + 255) / 256, 256, 0, stream>>>(ideg, invdeg);
    scan_kernel<<<1, SCAN_T, 0, stream>>>(ideg, row_start);
    fill_kernel<<<(N_EDGES + 255) / 256, 256, 0, stream>>>(src, dst, row_start, cursor, csr_src);

    // ---------------- layer 1 (A=x, K=300) ----------------
    prep_w<<<(256 * KP1 + 255) / 256, 256, 0, stream>>>(W1l, W1r, IN_CH, KP1, Bhi, Blo);
    gemm_mfma<<<gemm_grid, 256, 0, stream>>>(x, N_NODES, IN_CH, KP1, Bhi, Blo, b1, buf0, buf1);
    gather_agg<<<gather_grid, 256, 0, stream>>>(buf0, row_start, csr_src, invdeg, buf1);
    hipMemsetAsync(sums, 0, 2 * HID * sizeof(float), stream);
    bn_stats<<<256, 256, 0, stream>>>(buf1, sums);
    bn_finalize<<<1, 128, 0, stream>>>(sums, g1, be1, ss);
    bn_apply_relu<<<apply_grid, 256, 0, stream>>>(buf1, ss);

    // ---------------- layer 2 (A=buf1, K=128) ----------------
    prep_w<<<(256 * HID + 255) / 256, 256, 0, stream>>>(W2l, W2r, HID, HID, Bhi, Blo);
    gemm_mfma<<<gemm_grid, 256, 0, stream>>>(buf1, N_NODES, HID, HID, Bhi, Blo, b2, buf0, buf2);
    gather_agg<<<gather_grid, 256, 0, stream>>>(buf0, row_start, csr_src, invdeg, buf2);
    hipMemsetAsync(sums, 0, 2 * HID * sizeof(float), stream);
    bn_stats<<<256, 256, 0, stream>>>(buf2, sums);
    bn_finalize<<<1, 128, 0, stream>>>(sums, g2, be2, ss);
    bn_apply_relu<<<apply_grid, 256, 0, stream>>>(buf2, ss);

    // ---------------- layer 3 (A=buf2, K=128) ----------------
    prep_w<<<(256 * HID + 255) / 256, 256, 0, stream>>>(W3l, W3r, HID, HID, Bhi, Blo);
    gemm_mfma<<<gemm_grid, 256, 0, stream>>>(buf2, N_NODES, HID, HID, Bhi, Blo, b3, buf0, buf1);
    gather_agg<<<gather_grid, 256, 0, stream>>>(buf0, row_start, csr_src, invdeg, buf1);
    hipMemsetAsync(sums, 0, 2 * HID * sizeof(float), stream);
    bn_stats<<<256, 256, 0, stream>>>(buf1, sums);
    bn_finalize<<<1, 128, 0, stream>>>(sums, g3, be3, ss);
    bn_apply_relu<<<apply_grid, 256, 0, stream>>>(buf1, ss);

    // ---------------- pool + head ----------------
    hipMemsetAsync(pooled, 0, (N_GRAPHS * HID + N_GRAPHS) * sizeof(float), stream);
    pool_kernel<<<pool_grid, 128, 0, stream>>>(buf1, batch, pooled, cnt);
    head_kernel<<<1, 128, 0, stream>>>(pooled, cnt, Wc, bc, outp);
}